// Round 2
// baseline (17818.748 us; speedup 1.0000x reference)
//
#include <hip/hip_runtime.h>
#include <hip/hip_bf16.h>

// ---------------------------------------------------------------------------
// LSTMTagger: char-LSTM (4096x16, H=128) -> word-LSTM (serial 4096, H=512)
//             -> linear(64) + log_softmax.
// Wire dtype of float tensors is UNKNOWN (f32 per reference, bf16 per test
// label) -> detected at runtime from char_emb bit patterns; all kernels
// dual-path on a device-side flag (ws[0]): 1 = bf16, 0 = f32.
//
// Workspace layout (float offsets):
//   flag    [16]        dtype flag (int at ws[0])
//   cembf   [8192]      char_emb f32
//   cWihf   [32768]     char_Wih f32
//   cbihf   [512]       char_bih f32
//   cbhhf   [512]       char_bhh f32
//   cWhhf   [65536]     char_Whh f32
//   bihf    [2048]      word bih f32
//   bhhf    [2048]      word bhh f32
//   W1T     [32768]     W1 transposed (512x64) f32
//   cge     [128*512]   char-gate table: cemb@cWih^T + cbih + cbhh
//   charh   [4096*128]  char-LSTM final hidden, f32
//   xp2     [4096*2048] word x-part gates (+both biases), stored BF16
//   hh      [4096*512]  word hidden history f32 (comm medium, 0xFF sentinel)
// total ~28.1 MB
// ---------------------------------------------------------------------------

#define OFF_FLAG  0
#define OFF_CEMB  16
#define OFF_CWIH  8208
#define OFF_CBIH  40976
#define OFF_CBHH  41488
#define OFF_CWHH  42000
#define OFF_BIH   107536
#define OFF_BHH   109584
#define OFF_W1T   111632
#define OFF_CGE   144400
#define OFF_CH    209936
#define OFF_XP2   734224
#define OFF_HH    4928528

#define SENT 0xFFFFFFFFu

__device__ __forceinline__ float sigf(float x) { return 1.0f / (1.0f + __expf(-x)); }
__device__ __forceinline__ float tanh_f(float x) { return 2.0f * sigf(2.0f * x) - 1.0f; }
__device__ __forceinline__ float b2f_lo(unsigned u) { return __uint_as_float(u << 16); }
__device__ __forceinline__ float b2f_hi(unsigned u) { return __uint_as_float(u & 0xFFFF0000u); }

// ---- D0: dtype detect. Bits [14:7] of a word = low-half bf16 exponent.
// bf16 N(0,1) data: always in [100,140]. f32 data: those are mantissa bits,
// ~uniform -> in-range with p~0.16. Vote across 64 words.
__global__ void detect_kernel(const unsigned* __restrict__ w, int* __restrict__ flagp) {
    unsigned v = w[threadIdx.x];
    unsigned e = (v >> 7) & 0xFF;
    int inr = (e >= 100 && e <= 140) ? 1 : 0;
    unsigned long long m = __ballot(inr);
    if (threadIdx.x == 0) flagp[0] = (__popcll(m) >= 56) ? 1 : 0;
}

// ---- K0: (bf16|f32) -> f32 convert ---------------------------------------
__global__ void convf_kernel(const void* __restrict__ s, float* __restrict__ d,
                             int n, const int* __restrict__ flagp) {
    int i = blockIdx.x * 256 + threadIdx.x;
    if (i >= n) return;
    d[i] = flagp[0] ? __bfloat162float(((const __hip_bfloat16*)s)[i])
                    : ((const float*)s)[i];
}

// ---- K0b: W1 (64x512) -> W1T (512x64) f32 --------------------------------
__global__ void w1t_kernel(const void* __restrict__ W1, float* __restrict__ W1T,
                           const int* __restrict__ flagp) {
    int i = blockIdx.x * 256 + threadIdx.x;   // 0..32767
    int j = i & 63, k = i >> 6;
    W1T[i] = flagp[0] ? __bfloat162float(((const __hip_bfloat16*)W1)[j * 512 + k])
                      : ((const float*)W1)[j * 512 + k];
}

// ---- K1: char gate table: cge[c][j] = emb[c] . cWih[j] + cbih[j] + cbhh[j]
__global__ void __launch_bounds__(256) cge_kernel(
    const float* __restrict__ cemb, const float* __restrict__ cWih,
    const float* __restrict__ cbih, const float* __restrict__ cbhh,
    float* __restrict__ cge)
{
    __shared__ float xe[64];
    int c = blockIdx.x, tid = threadIdx.x;
    if (tid < 64) xe[tid] = cemb[c * 64 + tid];
    __syncthreads();
#pragma unroll
    for (int rep = 0; rep < 2; ++rep) {
        int j = rep * 256 + tid;
        float acc = cbih[j] + cbhh[j];
#pragma unroll 8
        for (int k = 0; k < 64; ++k)
            acc += xe[k] * cWih[j * 64 + k];
        cge[c * 512 + j] = acc;
    }
}

// ---- K2: char LSTM. 16 words/block; thread (wl,sl) owns word wl,
//          h-slots sl*8..sl*8+8. 16 steps with length masking. -------------
__global__ void __launch_bounds__(256) char_lstm_kernel(
    const float* __restrict__ cge, const float* __restrict__ Whh,
    const int* __restrict__ chars, const int* __restrict__ lens,
    float* __restrict__ char_h)
{
    __shared__ float hls[16][128];
    int tid = threadIdx.x;
    int wl = tid >> 4, sl = tid & 15;
    int w = blockIdx.x * 16 + wl;
    int len = lens[w];
    const int* cw = chars + w * 16;
    float c[8];
#pragma unroll
    for (int q = 0; q < 8; ++q) { c[q] = 0.0f; hls[wl][sl * 8 + q] = 0.0f; }

    for (int t = 0; t < 16; ++t) {
        __syncthreads();                 // prev h writes done
        int ch = cw[t];
        const float* xg = cge + ch * 512;
        float acc[4][8];
#pragma unroll
        for (int g = 0; g < 4; ++g)
#pragma unroll
            for (int q = 0; q < 8; ++q)
                acc[g][q] = xg[g * 128 + sl * 8 + q];

        const float4* h4 = (const float4*)hls[wl];
#pragma unroll
        for (int g = 0; g < 4; ++g) {
            const float4* wbase = ((const float4*)Whh) + (g * 128 + sl * 8) * 32;
            for (int k4 = 0; k4 < 32; ++k4) {
                float4 hv = h4[k4];
#pragma unroll
                for (int q = 0; q < 8; ++q) {
                    float4 wv = wbase[q * 32 + k4];
                    acc[g][q] += wv.x * hv.x + wv.y * hv.y + wv.z * hv.z + wv.w * hv.w;
                }
            }
        }
        __syncthreads();                 // all reads of h done
        if (t < len) {
#pragma unroll
            for (int q = 0; q < 8; ++q) {
                float iv = sigf(acc[0][q]);
                float fv = sigf(acc[1][q]);
                float gv = tanh_f(acc[2][q]);
                float ov = sigf(acc[3][q]);
                c[q] = fv * c[q] + iv * gv;
                hls[wl][sl * 8 + q] = ov * tanh_f(c[q]);
            }
        }
    }
    __syncthreads();
#pragma unroll
    for (int q = 0; q < 8; ++q)
        char_h[w * 128 + sl * 8 + q] = hls[wl][sl * 8 + q];
}

// ---- K3: word x-part gates (bf16 out):
//   xp2[t][r] = Wih[r] . feat[t] + bih[r] + bhh[r],
//   feat[t] = [word_emb[x[t]] (256) | char_h[t] (128)]. Wih read raw. ------
__global__ void __launch_bounds__(256) xp2_kernel(
    const void* __restrict__ wemb, const int* __restrict__ x,
    const float* __restrict__ char_h, const void* __restrict__ Wraw,
    const float* __restrict__ bih, const float* __restrict__ bhh,
    __hip_bfloat16* __restrict__ xp2, const int* __restrict__ flagp)
{
    __shared__ float feat[16][384];
    int flag = flagp[0];
    int tid = threadIdx.x, tl = tid >> 4, sl = tid & 15;
    int t = blockIdx.x * 16 + tl;
    int xw = x[t];
    for (int idx = sl; idx < 384; idx += 16) {
        float v;
        if (idx < 256)
            v = flag ? __bfloat162float(((const __hip_bfloat16*)wemb)[(size_t)xw * 256 + idx])
                     : ((const float*)wemb)[(size_t)xw * 256 + idx];
        else
            v = char_h[t * 128 + (idx - 256)];
        feat[tl][idx] = v;
    }
    __syncthreads();

    const float4* f4 = (const float4*)feat[tl];
    for (int rb = 0; rb < 4; ++rb) {
        int r0 = rb * 512 + sl * 32;
        for (int qc = 0; qc < 4; ++qc) {
            int rr = r0 + qc * 8;
            float acc[8];
#pragma unroll
            for (int q = 0; q < 8; ++q)
                acc[q] = bih[rr + q] + bhh[rr + q];
            if (!flag) {
                const float4* wb = ((const float4*)Wraw) + (size_t)rr * 96;
                for (int k4 = 0; k4 < 96; ++k4) {
                    float4 fv = f4[k4];
#pragma unroll
                    for (int q = 0; q < 8; ++q) {
                        float4 wv = wb[q * 96 + k4];
                        acc[q] += wv.x * fv.x + wv.y * fv.y + wv.z * fv.z + wv.w * fv.w;
                    }
                }
            } else {
                const uint2* wb = ((const uint2*)Wraw) + (size_t)rr * 96; // 4 bf16 per uint2
                for (int k4 = 0; k4 < 96; ++k4) {
                    float4 fv = f4[k4];
#pragma unroll
                    for (int q = 0; q < 8; ++q) {
                        uint2 wv = wb[q * 96 + k4];
                        acc[q] += b2f_lo(wv.x) * fv.x + b2f_hi(wv.x) * fv.y
                                + b2f_lo(wv.y) * fv.z + b2f_hi(wv.y) * fv.w;
                    }
                }
            }
#pragma unroll
            for (int q = 0; q < 8; ++q)
                xp2[(size_t)t * 2048 + rr + q] = __float2bfloat16(acc[q]);
        }
    }
}

// ---- K5: serial word LSTM. 256 WGs x 64 threads (1 wave each).
//   WG wg owns h-slots {2wg, 2wg+1}. lane = rl*8+g; rl = slot_local*4+gate;
//   lane holds Whh[gate*512+slot][g*64 .. g*64+64) in registers (raw load).
//   h history write-once; 0xFF sentinel dwords double as ready flags. ------
__global__ void __launch_bounds__(64) word_lstm_kernel(
    const __hip_bfloat16* __restrict__ xp2, const void* __restrict__ Whh_raw,
    float* __restrict__ h_hist, const int* __restrict__ flagp)
{
    __shared__ float hbuf[512];
    int flag = flagp[0];
    int wg = blockIdx.x;
    int lane = threadIdx.x;
    int rl = lane >> 3, g = lane & 7;
    int slot_local = rl >> 2, gate = rl & 3;
    int slot = wg * 2 + slot_local;
    int grow = gate * 512 + slot;

    float4 wreg[16];
    if (!flag) {
        const float4* wrow = (const float4*)((const float*)Whh_raw + (size_t)grow * 512 + g * 64);
#pragma unroll
        for (int i = 0; i < 16; ++i) wreg[i] = wrow[i];
    } else {
        const uint2* wrow = (const uint2*)((const unsigned short*)Whh_raw + (size_t)grow * 512 + g * 64);
#pragma unroll
        for (int i = 0; i < 16; ++i) {
            uint2 u = wrow[i];
            wreg[i] = make_float4(b2f_lo(u.x), b2f_hi(u.x), b2f_lo(u.y), b2f_hi(u.y));
        }
    }

    unsigned* hview = (unsigned*)h_hist;
    float c = 0.0f;

    for (int t = 0; t < 4096; ++t) {
        float xv = __bfloat162float(xp2[(size_t)t * 2048 + grow]); // h-independent

        if (t == 0) {
#pragma unroll
            for (int i = 0; i < 8; ++i) hbuf[lane * 8 + i] = 0.0f;
        } else {
            const unsigned* src = hview + (size_t)(t - 1) * 512 + lane * 8;
            unsigned v[8];
            unsigned spins = 0;
            bool bail = false;
            for (;;) {
#pragma unroll
                for (int i = 0; i < 8; ++i)
                    v[i] = __hip_atomic_load(src + i, __ATOMIC_RELAXED,
                                             __HIP_MEMORY_SCOPE_AGENT);
                int ok = 1;
#pragma unroll
                for (int i = 0; i < 8; ++i) ok &= (v[i] != SENT);
                if (__all(ok)) break;
                if (++spins > (1u << 22)) { bail = true; break; }
            }
            if (bail) {                       // distinct failure signature
#pragma unroll
                for (int i = 0; i < 8; ++i) v[i] = __float_as_uint(12345.0f);
            }
#pragma unroll
            for (int i = 0; i < 8; ++i) hbuf[lane * 8 + i] = __uint_as_float(v[i]);
        }
        __syncthreads();   // order LDS write -> read (single wave: cheap)

        float acc = 0.0f;
        const float4* h4 = (const float4*)(hbuf + g * 64);
#pragma unroll
        for (int i = 0; i < 16; ++i) {
            float4 hv = h4[i];
            acc += wreg[i].x * hv.x + wreg[i].y * hv.y +
                   wreg[i].z * hv.z + wreg[i].w * hv.w;
        }
        // sum the 8 k-slices of this gate row (lanes rl*8 .. rl*8+7)
        acc += __shfl_xor(acc, 1);
        acc += __shfl_xor(acc, 2);
        acc += __shfl_xor(acc, 4);
        float gv = acc + xv;

        int base = lane & 32;                      // slot group base lane
        float iv = __shfl(gv, base + 0);
        float fv = __shfl(gv, base + 8);
        float gg = __shfl(gv, base + 16);
        float ov = __shfl(gv, base + 24);
        c = sigf(fv) * c + sigf(iv) * tanh_f(gg);
        float h = sigf(ov) * tanh_f(c);

        if ((lane & 31) == 0)
            __hip_atomic_store(hview + (size_t)t * 512 + slot, __float_as_uint(h),
                               __ATOMIC_RELAXED, __HIP_MEMORY_SCOPE_AGENT);
        __syncthreads();   // keep next iter's LDS writes after all reads
    }
}

// ---- K6: logits + log_softmax. one wave per timestep. --------------------
__global__ void __launch_bounds__(64) out_kernel(
    const float* __restrict__ h_hist, const float* __restrict__ W1T,
    const void* __restrict__ b1raw, void* __restrict__ out,
    const int* __restrict__ flagp)
{
    __shared__ float hb[512];
    int flag = flagp[0];
    int t = blockIdx.x, j = threadIdx.x;
    const float4* src = (const float4*)(h_hist + (size_t)t * 512);
    ((float4*)hb)[j * 2] = src[j * 2];
    ((float4*)hb)[j * 2 + 1] = src[j * 2 + 1];
    __syncthreads();

    float acc = flag ? __bfloat162float(((const __hip_bfloat16*)b1raw)[j])
                     : ((const float*)b1raw)[j];
#pragma unroll 8
    for (int k = 0; k < 512; ++k)
        acc += hb[k] * W1T[k * 64 + j];

    float m = acc;
#pragma unroll
    for (int o = 32; o; o >>= 1) m = fmaxf(m, __shfl_xor(m, o));
    float e = __expf(acc - m);
    float s = e;
#pragma unroll
    for (int o = 32; o; o >>= 1) s += __shfl_xor(s, o);
    float r = acc - m - __logf(s);
    if (flag) ((__hip_bfloat16*)out)[t * 64 + j] = __float2bfloat16(r);
    else      ((float*)out)[t * 64 + j] = r;
}

extern "C" void kernel_launch(void* const* d_in, const int* in_sizes, int n_in,
                              void* d_out, int out_size, void* d_ws, size_t ws_size,
                              hipStream_t stream)
{
    (void)in_sizes; (void)n_in; (void)out_size; (void)ws_size;
    const void* char_emb = d_in[0];
    const void* char_Wih = d_in[1];
    const void* char_Whh = d_in[2];
    const void* char_bih = d_in[3];
    const void* char_bhh = d_in[4];
    const void* word_emb = d_in[5];
    const void* Wih      = d_in[6];
    const void* Whh      = d_in[7];
    const void* bih      = d_in[8];
    const void* bhh      = d_in[9];
    const void* W1       = d_in[10];
    const void* b1       = d_in[11];
    const int* x     = (const int*)d_in[12];
    const int* chars = (const int*)d_in[13];
    const int* lens  = (const int*)d_in[14];

    float* ws    = (float*)d_ws;
    int*   flagp = (int*)(ws + OFF_FLAG);
    float* cembf = ws + OFF_CEMB;
    float* cWihf = ws + OFF_CWIH;
    float* cbihf = ws + OFF_CBIH;
    float* cbhhf = ws + OFF_CBHH;
    float* cWhhf = ws + OFF_CWHH;
    float* bihf  = ws + OFF_BIH;
    float* bhhf  = ws + OFF_BHH;
    float* W1T   = ws + OFF_W1T;
    float* cge   = ws + OFF_CGE;
    float* charh = ws + OFF_CH;
    __hip_bfloat16* xp2 = (__hip_bfloat16*)(ws + OFF_XP2);
    float* hh    = ws + OFF_HH;

    // sentinel-fill h history (data-as-flag for the serial kernel)
    hipMemsetAsync(hh, 0xFF, (size_t)4096 * 512 * 4, stream);

    detect_kernel<<<1, 64, 0, stream>>>((const unsigned*)char_emb, flagp);

    convf_kernel<<<(8192 + 255) / 256, 256, 0, stream>>>(char_emb, cembf, 8192, flagp);
    convf_kernel<<<(32768 + 255) / 256, 256, 0, stream>>>(char_Wih, cWihf, 32768, flagp);
    convf_kernel<<<2, 256, 0, stream>>>(char_bih, cbihf, 512, flagp);
    convf_kernel<<<2, 256, 0, stream>>>(char_bhh, cbhhf, 512, flagp);
    convf_kernel<<<(65536 + 255) / 256, 256, 0, stream>>>(char_Whh, cWhhf, 65536, flagp);
    convf_kernel<<<8, 256, 0, stream>>>(bih, bihf, 2048, flagp);
    convf_kernel<<<8, 256, 0, stream>>>(bhh, bhhf, 2048, flagp);
    w1t_kernel<<<128, 256, 0, stream>>>(W1, W1T, flagp);

    cge_kernel<<<128, 256, 0, stream>>>(cembf, cWihf, cbihf, cbhhf, cge);
    char_lstm_kernel<<<256, 256, 0, stream>>>(cge, cWhhf, chars, lens, charh);
    xp2_kernel<<<256, 256, 0, stream>>>(word_emb, x, charh, Wih, bihf, bhhf, xp2, flagp);
    word_lstm_kernel<<<256, 64, 0, stream>>>(xp2, Whh, hh, flagp);
    out_kernel<<<4096, 64, 0, stream>>>(hh, W1T, b1, d_out, flagp);
}